// Round 5
// baseline (2574.273 us; speedup 1.0000x reference)
//
#include <hip/hip_runtime.h>
#include <math.h>

namespace {

constexpr int PP = 20;   // points per sample
constexpr int KK = 8;    // k nearest neighbors
constexpr int XS = 516;  // padded feature row stride (floats); 516*4B = 2064B, 16B-aligned, breaks %32 bank aliasing

struct __align__(16) Smem {
  float X[PP][XS];    // current features (max 20x512), reused across layers
  float A[PP][PP];    // normalized adjacency (incl. self loops)
  float d2[PP][PP];   // pairwise squared distances (scratch)
  float sq[PP];
  float dinv[PP];
  int   knn[PP][KK];
  int   cnt[PP];
  float m[128];
  float yv[64];
  float logits[3];
};

__device__ __forceinline__ void fma4(float4& a, float s, const float4& w) {
  a.x = fmaf(s, w.x, a.x);
  a.y = fmaf(s, w.y, a.y);
  a.z = fmaf(s, w.z, a.z);
  a.w = fmaf(s, w.w, a.w);
}

template<int DIN, int DOUT>
__device__ void gcn_layer(Smem& sm, const float* __restrict__ W,
                          const float* __restrict__ b, int tid) {
  // ---- pairwise dots (i<=j), same formula as reference: sq[i]+sq[j]-2*dot ----
  if (tid < 210) {
    int i = 0, rem = tid;
    while (rem >= PP - i) { rem -= PP - i; ++i; }
    int j = i + rem;
    const float4* xi = reinterpret_cast<const float4*>(sm.X[i]);
    const float4* xj = reinterpret_cast<const float4*>(sm.X[j]);
    float ax = 0.f, ay = 0.f, az = 0.f, aw = 0.f;
    #pragma unroll 4
    for (int d = 0; d < DIN / 4; ++d) {
      float4 a = xi[d], bb = xj[d];
      ax = fmaf(a.x, bb.x, ax);
      ay = fmaf(a.y, bb.y, ay);
      az = fmaf(a.z, bb.z, az);
      aw = fmaf(a.w, bb.w, aw);
    }
    float dot = (ax + ay) + (az + aw);
    sm.d2[i][j] = dot;
    if (i != j) sm.d2[j][i] = dot;
    else        sm.sq[i] = dot;
  }
  if (tid < PP) sm.cnt[tid] = 0;
  __syncthreads();
  // ---- dots -> squared distances (diag exactly 0) ----
  for (int e = tid; e < PP * PP; e += 256) {
    int i = e / PP, j = e % PP;
    float v = (i == j) ? 0.0f : (sm.sq[i] + sm.sq[j] - 2.0f * sm.d2[i][j]);
    sm.d2[i][j] = v;
  }
  __syncthreads();
  // ---- stable-argsort rank per element; ranks 1..K are the neighbors ----
  for (int e = tid; e < PP * PP; e += 256) {
    int i = e / PP, j = e % PP;
    float vj = sm.d2[i][j];
    int r = 0;
    #pragma unroll
    for (int l = 0; l < PP; ++l) {
      float vl = sm.d2[i][l];
      r += (vl < vj || (vl == vj && l < j)) ? 1 : 0;
    }
    if (r >= 1 && r <= KK) sm.knn[i][r - 1] = j;
  }
  __syncthreads();
  // ---- in-degree (target side) + self loop -> dinv ----
  if (tid < PP * KK) atomicAdd(&sm.cnt[sm.knn[tid / KK][tid % KK]], 1);
  __syncthreads();
  if (tid < PP) sm.dinv[tid] = 1.0f / sqrtf((float)(sm.cnt[tid] + 1));
  __syncthreads();
  // ---- A[t][s] = dinv[t]*dinv[s]*[t in knn(s)] + (t==s)*dinv[t]^2 ----
  for (int e = tid; e < PP * PP; e += 256) {
    int t = e / PP, s = e % PP;
    float hit = 0.0f;
    #pragma unroll
    for (int k = 0; k < KK; ++k) hit += (sm.knn[s][k] == t) ? 1.0f : 0.0f;
    float a = hit * sm.dinv[t] * sm.dinv[s];
    if (t == s) a += sm.dinv[t] * sm.dinv[t];
    sm.A[t][s] = a;
  }
  __syncthreads();
  // ---- Z = A @ X in registers, write back over X ----
  {
    constexpr int NF4 = DIN / 4;
    constexpr int RG  = 256 / NF4;
    constexpr int NP  = (PP + RG - 1) / RG;
    const int c  = tid % NF4;
    const int rg = tid / NF4;
    float4 z[NP];
    #pragma unroll
    for (int u = 0; u < NP; ++u) z[u] = make_float4(0.f, 0.f, 0.f, 0.f);
    for (int s = 0; s < PP; ++s) {
      float4 xv = reinterpret_cast<const float4*>(sm.X[s])[c];
      #pragma unroll
      for (int u = 0; u < NP; ++u) {
        int p = rg + u * RG;
        float av = (p < PP) ? sm.A[p][s] : 0.0f;
        fma4(z[u], av, xv);
      }
    }
    __syncthreads();  // all reads of X done before overwrite
    #pragma unroll
    for (int u = 0; u < NP; ++u) {
      int p = rg + u * RG;
      if (p < PP) reinterpret_cast<float4*>(sm.X[p])[c] = z[u];
    }
    __syncthreads();
  }
  // ---- X = relu(Z @ W + b) ----
  {
    constexpr int NF4 = DOUT / 4;
    constexpr int RG  = 256 / NF4;
    constexpr int NP  = (PP + RG - 1) / RG;
    const int c  = tid % NF4;
    const int rg = tid / NF4;
    const float4* W4p = reinterpret_cast<const float4*>(W);
    float4 acc[NP];
    #pragma unroll
    for (int u = 0; u < NP; ++u) acc[u] = make_float4(0.f, 0.f, 0.f, 0.f);
    for (int d4 = 0; d4 < DIN / 4; ++d4) {
      float4 xq[NP];
      #pragma unroll
      for (int u = 0; u < NP; ++u) {
        int p = rg + u * RG;
        xq[u] = (p < PP) ? reinterpret_cast<const float4*>(sm.X[p])[d4]
                         : make_float4(0.f, 0.f, 0.f, 0.f);
      }
      #pragma unroll
      for (int k = 0; k < 4; ++k) {
        float4 w = W4p[(size_t)(d4 * 4 + k) * NF4 + c];
        #pragma unroll
        for (int u = 0; u < NP; ++u) {
          float xs = (k == 0) ? xq[u].x : (k == 1) ? xq[u].y : (k == 2) ? xq[u].z : xq[u].w;
          fma4(acc[u], xs, w);
        }
      }
    }
    __syncthreads();  // all reads of Z done before overwrite
    float4 bb = reinterpret_cast<const float4*>(b)[c];
    #pragma unroll
    for (int u = 0; u < NP; ++u) {
      int p = rg + u * RG;
      if (p < PP) {
        float4 o;
        o.x = fmaxf(acc[u].x + bb.x, 0.0f);
        o.y = fmaxf(acc[u].y + bb.y, 0.0f);
        o.z = fmaxf(acc[u].z + bb.z, 0.0f);
        o.w = fmaxf(acc[u].w + bb.w, 0.0f);
        reinterpret_cast<float4*>(sm.X[p])[c] = o;
      }
    }
    __syncthreads();
  }
}

__global__ __launch_bounds__(256, 3)
void gnn_kernel(const float* __restrict__ x,
                const float* __restrict__ W1, const float* __restrict__ b1,
                const float* __restrict__ W2, const float* __restrict__ b2,
                const float* __restrict__ W3, const float* __restrict__ b3,
                const float* __restrict__ W4, const float* __restrict__ b4,
                const float* __restrict__ W5, const float* __restrict__ b5,
                float* __restrict__ out) {
  __shared__ Smem sm;
  const int tid = threadIdx.x;
  const int blk = blockIdx.x;
  // load sample (20x128) into padded LDS rows, coalesced f4
  const float4* xin = reinterpret_cast<const float4*>(x + (size_t)blk * PP * 128);
  for (int e = tid; e < PP * 32; e += 256) {
    int p = e >> 5, c = e & 31;
    reinterpret_cast<float4*>(sm.X[p])[c] = xin[e];
  }
  __syncthreads();

  gcn_layer<128, 256>(sm, W1, b1, tid);
  gcn_layer<256, 512>(sm, W2, b2, tid);
  gcn_layer<512, 128>(sm, W3, b3, tid);

  // mean over the 20 points -> m[128]
  if (tid < 32) {
    float4 s = make_float4(0.f, 0.f, 0.f, 0.f);
    for (int p = 0; p < PP; ++p) {
      float4 v = reinterpret_cast<const float4*>(sm.X[p])[tid];
      s.x += v.x; s.y += v.y; s.z += v.z; s.w += v.w;
    }
    const float inv = 1.0f / (float)PP;
    s.x *= inv; s.y *= inv; s.z *= inv; s.w *= inv;
    reinterpret_cast<float4*>(sm.m)[tid] = s;
  }
  __syncthreads();
  // FC1: relu(m @ W4 + b4) -> yv[64]
  if (tid < 64) {
    float a = 0.f;
    #pragma unroll 4
    for (int d = 0; d < 128; ++d) a = fmaf(sm.m[d], W4[d * 64 + tid], a);
    sm.yv[tid] = fmaxf(a + b4[tid], 0.f);
  }
  __syncthreads();
  // FC2 logits
  if (tid < 3) {
    float a = 0.f;
    #pragma unroll 4
    for (int d = 0; d < 64; ++d) a = fmaf(sm.yv[d], W5[d * 3 + tid], a);
    sm.logits[tid] = a + b5[tid];
  }
  __syncthreads();
  // softmax (max-subtracted, matches jax.nn.softmax)
  if (tid < 3) {
    float l0 = sm.logits[0], l1 = sm.logits[1], l2 = sm.logits[2];
    float mx = fmaxf(l0, fmaxf(l1, l2));
    float s = expf(l0 - mx) + expf(l1 - mx) + expf(l2 - mx);
    out[(size_t)blk * 3 + tid] = expf(sm.logits[tid] - mx) / s;
  }
}

}  // namespace

extern "C" void kernel_launch(void* const* d_in, const int* in_sizes, int n_in,
                              void* d_out, int out_size, void* d_ws, size_t ws_size,
                              hipStream_t stream) {
  const float* x  = (const float*)d_in[0];
  const float* W1 = (const float*)d_in[1];
  const float* b1 = (const float*)d_in[2];
  const float* W2 = (const float*)d_in[3];
  const float* b2 = (const float*)d_in[4];
  const float* W3 = (const float*)d_in[5];
  const float* b3 = (const float*)d_in[6];
  const float* W4 = (const float*)d_in[7];
  const float* b4 = (const float*)d_in[8];
  const float* W5 = (const float*)d_in[9];
  const float* b5 = (const float*)d_in[10];
  float* out = (float*)d_out;
  const int N = in_sizes[0] / (PP * 128);
  gnn_kernel<<<dim3(N), dim3(256), 0, stream>>>(x, W1, b1, W2, b2, W3, b3,
                                                W4, b4, W5, b5, out);
}

// Round 7
// 2542.139 us; speedup vs baseline: 1.0126x; 1.0126x over previous
//
#include <hip/hip_runtime.h>
#include <math.h>

namespace {

constexpr int PP = 20;   // points per sample
constexpr int KK = 8;    // k nearest neighbors
constexpr int XS = 516;  // padded feature row stride (floats); 2064B, breaks %32 bank aliasing

struct __align__(16) Smem {
  float X[PP][XS];    // current features (max 20x512), reused across layers
  float A[PP][PP];    // normalized adjacency (incl. self loops)
  float d2[PP][PP];   // pairwise squared distances (scratch)
  float sq[PP];
  float dinv[PP];
  int   knn[PP][KK];
  int   cnt[PP];
  float m[128];
  float yv[64];
  float logits[3];
};

__device__ __forceinline__ void fma4(float4& a, float s, const float4& w) {
  a.x = fmaf(s, w.x, a.x);
  a.y = fmaf(s, w.y, a.y);
  a.z = fmaf(s, w.z, a.z);
  a.w = fmaf(s, w.w, a.w);
}

template<int DIN, int DOUT>
__device__ void gcn_layer(Smem& sm, const float* __restrict__ W,
                          const float* __restrict__ b, int tid) {
  // ---- pairwise dots (i<=j), same formula as reference: sq[i]+sq[j]-2*dot ----
  if (tid < 210) {
    int i = 0, rem = tid;
    while (rem >= PP - i) { rem -= PP - i; ++i; }
    int j = i + rem;
    const float4* xi = reinterpret_cast<const float4*>(sm.X[i]);
    const float4* xj = reinterpret_cast<const float4*>(sm.X[j]);
    float ax = 0.f, ay = 0.f, az = 0.f, aw = 0.f;
    #pragma unroll 4
    for (int d = 0; d < DIN / 4; ++d) {
      float4 a = xi[d], bb = xj[d];
      ax = fmaf(a.x, bb.x, ax);
      ay = fmaf(a.y, bb.y, ay);
      az = fmaf(a.z, bb.z, az);
      aw = fmaf(a.w, bb.w, aw);
    }
    float dot = (ax + ay) + (az + aw);
    sm.d2[i][j] = dot;
    if (i != j) sm.d2[j][i] = dot;
    else        sm.sq[i] = dot;
  }
  if (tid < PP) sm.cnt[tid] = 0;
  __syncthreads();
  // ---- dots -> squared distances (diag exactly 0) ----
  for (int e = tid; e < PP * PP; e += 256) {
    int i = e / PP, j = e % PP;
    float v = (i == j) ? 0.0f : (sm.sq[i] + sm.sq[j] - 2.0f * sm.d2[i][j]);
    sm.d2[i][j] = v;
  }
  __syncthreads();
  // ---- stable-argsort rank per element; ranks 1..K are the neighbors ----
  for (int e = tid; e < PP * PP; e += 256) {
    int i = e / PP, j = e % PP;
    float vj = sm.d2[i][j];
    int r = 0;
    #pragma unroll
    for (int l = 0; l < PP; ++l) {
      float vl = sm.d2[i][l];
      r += (vl < vj || (vl == vj && l < j)) ? 1 : 0;
    }
    if (r >= 1 && r <= KK) sm.knn[i][r - 1] = j;
  }
  __syncthreads();
  // ---- in-degree (target side) + self loop -> dinv ----
  if (tid < PP * KK) atomicAdd(&sm.cnt[sm.knn[tid / KK][tid % KK]], 1);
  __syncthreads();
  if (tid < PP) sm.dinv[tid] = 1.0f / sqrtf((float)(sm.cnt[tid] + 1));
  __syncthreads();
  // ---- A[t][s] = dinv[t]*dinv[s]*[t in knn(s)] + (t==s)*dinv[t]^2 ----
  for (int e = tid; e < PP * PP; e += 256) {
    int t = e / PP, s = e % PP;
    float hit = 0.0f;
    #pragma unroll
    for (int k = 0; k < KK; ++k) hit += (sm.knn[s][k] == t) ? 1.0f : 0.0f;
    float a = hit * sm.dinv[t] * sm.dinv[s];
    if (t == s) a += sm.dinv[t] * sm.dinv[t];
    sm.A[t][s] = a;
  }
  __syncthreads();
  // ---- Z = A @ X in registers, write back over X ----
  {
    constexpr int NF4 = DIN / 4;
    constexpr int RG  = 256 / NF4;
    constexpr int NP  = (PP + RG - 1) / RG;
    const int c  = tid % NF4;
    const int rg = tid / NF4;
    float4 z[NP];
    #pragma unroll
    for (int u = 0; u < NP; ++u) z[u] = make_float4(0.f, 0.f, 0.f, 0.f);
    for (int s = 0; s < PP; ++s) {
      float4 xv = reinterpret_cast<const float4*>(sm.X[s])[c];
      #pragma unroll
      for (int u = 0; u < NP; ++u) {
        int p = rg + u * RG;
        float av = (p < PP) ? sm.A[p][s] : 0.0f;
        fma4(z[u], av, xv);
      }
    }
    __syncthreads();  // all reads of X done before overwrite
    #pragma unroll
    for (int u = 0; u < NP; ++u) {
      int p = rg + u * RG;
      if (p < PP) reinterpret_cast<float4*>(sm.X[p])[c] = z[u];
    }
    __syncthreads();
  }
  // ---- X = relu(Z @ W + b) ----
  // Restructured vs R0: hold 4 w-row float4s, stream one xv per point inside
  // the unrolled point loop. Live regs: acc[NP](<=40) + w(16) + xv(4) ~= 65,
  // eliminating the xq[NP] array (40 VGPRs) that caused scratch spills.
  // Accumulation order per output element unchanged (d4-major, k=0..3).
  {
    constexpr int NF4 = DOUT / 4;
    constexpr int RG  = 256 / NF4;
    constexpr int NP  = (PP + RG - 1) / RG;
    constexpr bool EXACT = (NP * RG == PP);
    const int c  = tid % NF4;
    const int rg = tid / NF4;
    const float4* W4p = reinterpret_cast<const float4*>(W);
    float4 acc[NP];
    #pragma unroll
    for (int u = 0; u < NP; ++u) acc[u] = make_float4(0.f, 0.f, 0.f, 0.f);
    for (int d4 = 0; d4 < DIN / 4; ++d4) {
      const float4* wrow = W4p + (size_t)(d4 * 4) * NF4 + c;
      float4 w0 = wrow[0 * NF4];
      float4 w1 = wrow[1 * NF4];
      float4 w2 = wrow[2 * NF4];
      float4 w3 = wrow[3 * NF4];
      #pragma unroll
      for (int u = 0; u < NP; ++u) {
        int p = rg + u * RG;
        if (EXACT || p < PP) {
          float4 xv = reinterpret_cast<const float4*>(sm.X[p])[d4];
          fma4(acc[u], xv.x, w0);
          fma4(acc[u], xv.y, w1);
          fma4(acc[u], xv.z, w2);
          fma4(acc[u], xv.w, w3);
        }
      }
    }
    __syncthreads();  // all reads of Z done before overwrite
    float4 bb = reinterpret_cast<const float4*>(b)[c];
    #pragma unroll
    for (int u = 0; u < NP; ++u) {
      int p = rg + u * RG;
      if (EXACT || p < PP) {
        float4 o;
        o.x = fmaxf(acc[u].x + bb.x, 0.0f);
        o.y = fmaxf(acc[u].y + bb.y, 0.0f);
        o.z = fmaxf(acc[u].z + bb.z, 0.0f);
        o.w = fmaxf(acc[u].w + bb.w, 0.0f);
        reinterpret_cast<float4*>(sm.X[p])[c] = o;
      }
    }
    __syncthreads();
  }
}

__global__ __launch_bounds__(256, 3)
void gnn_kernel(const float* __restrict__ x,
                const float* __restrict__ W1, const float* __restrict__ b1,
                const float* __restrict__ W2, const float* __restrict__ b2,
                const float* __restrict__ W3, const float* __restrict__ b3,
                const float* __restrict__ W4, const float* __restrict__ b4,
                const float* __restrict__ W5, const float* __restrict__ b5,
                float* __restrict__ out) {
  __shared__ Smem sm;
  const int tid = threadIdx.x;
  const int blk = blockIdx.x;
  // load sample (20x128) into padded LDS rows, coalesced f4
  const float4* xin = reinterpret_cast<const float4*>(x + (size_t)blk * PP * 128);
  for (int e = tid; e < PP * 32; e += 256) {
    int p = e >> 5, c = e & 31;
    reinterpret_cast<float4*>(sm.X[p])[c] = xin[e];
  }
  __syncthreads();

  gcn_layer<128, 256>(sm, W1, b1, tid);
  gcn_layer<256, 512>(sm, W2, b2, tid);
  gcn_layer<512, 128>(sm, W3, b3, tid);

  // mean over the 20 points -> m[128]
  if (tid < 32) {
    float4 s = make_float4(0.f, 0.f, 0.f, 0.f);
    for (int p = 0; p < PP; ++p) {
      float4 v = reinterpret_cast<const float4*>(sm.X[p])[tid];
      s.x += v.x; s.y += v.y; s.z += v.z; s.w += v.w;
    }
    const float inv = 1.0f / (float)PP;
    s.x *= inv; s.y *= inv; s.z *= inv; s.w *= inv;
    reinterpret_cast<float4*>(sm.m)[tid] = s;
  }
  __syncthreads();
  // FC1: relu(m @ W4 + b4) -> yv[64]
  if (tid < 64) {
    float a = 0.f;
    #pragma unroll 4
    for (int d = 0; d < 128; ++d) a = fmaf(sm.m[d], W4[d * 64 + tid], a);
    sm.yv[tid] = fmaxf(a + b4[tid], 0.f);
  }
  __syncthreads();
  // FC2 logits
  if (tid < 3) {
    float a = 0.f;
    #pragma unroll 4
    for (int d = 0; d < 64; ++d) a = fmaf(sm.yv[d], W5[d * 3 + tid], a);
    sm.logits[tid] = a + b5[tid];
  }
  __syncthreads();
  // softmax (max-subtracted, matches jax.nn.softmax)
  if (tid < 3) {
    float l0 = sm.logits[0], l1 = sm.logits[1], l2 = sm.logits[2];
    float mx = fmaxf(l0, fmaxf(l1, l2));
    float s = expf(l0 - mx) + expf(l1 - mx) + expf(l2 - mx);
    out[(size_t)blk * 3 + tid] = expf(sm.logits[tid] - mx) / s;
  }
}

}  // namespace

extern "C" void kernel_launch(void* const* d_in, const int* in_sizes, int n_in,
                              void* d_out, int out_size, void* d_ws, size_t ws_size,
                              hipStream_t stream) {
  const float* x  = (const float*)d_in[0];
  const float* W1 = (const float*)d_in[1];
  const float* b1 = (const float*)d_in[2];
  const float* W2 = (const float*)d_in[3];
  const float* b2 = (const float*)d_in[4];
  const float* W3 = (const float*)d_in[5];
  const float* b3 = (const float*)d_in[6];
  const float* W4 = (const float*)d_in[7];
  const float* b4 = (const float*)d_in[8];
  const float* W5 = (const float*)d_in[9];
  const float* b5 = (const float*)d_in[10];
  float* out = (float*)d_out;
  const int N = in_sizes[0] / (PP * 128);
  gnn_kernel<<<dim3(N), dim3(256), 0, stream>>>(x, W1, b1, W2, b2, W3, b3,
                                                W4, b4, W5, b5, out);
}